// Round 17
// baseline (2939.847 us; speedup 1.0000x reference)
//
#include <hip/hip_runtime.h>
#include <math.h>

#define BB 64
#define SS 512
#define EE 256
#define HH 512

typedef unsigned long long ull;

// ---------------------------------------------------------------------------
// Projection GEMM (layer 0): out[m][n] = sum_k A[m][k]*Wih[n][k] + b1 + b2
// ---------------------------------------------------------------------------
template <int K>
__global__ __launch_bounds__(256) void k_proj(const float* __restrict__ Ain,
                                              const int* __restrict__ src,
                                              const float* __restrict__ emb,
                                              const float* __restrict__ Wih,
                                              const float* __restrict__ b1,
                                              const float* __restrict__ b2,
                                              float* __restrict__ out) {
    __shared__ __align__(16) float As[16][68];
    __shared__ __align__(16) float Bs[16][68];
    int tid = threadIdx.x;
    int m0 = blockIdx.x * 64;
    int n0 = blockIdx.y * 64;
    int tx = tid & 15, ty = tid >> 4;
    int lr = tid >> 2;
    int lc = (tid & 3) * 4;

    const float* arow;
    if (src) arow = emb + (size_t)src[m0 + lr] * EE;
    else     arow = Ain + (size_t)(m0 + lr) * K;
    const float* brow = Wih + (size_t)(n0 + lr) * K;

    float acc[4][4] = {};

    for (int k0 = 0; k0 < K; k0 += 16) {
        float4 av = *(const float4*)(arow + k0 + lc);
        float4 bv = *(const float4*)(brow + k0 + lc);
        __syncthreads();
        As[lc + 0][lr] = av.x; As[lc + 1][lr] = av.y;
        As[lc + 2][lr] = av.z; As[lc + 3][lr] = av.w;
        Bs[lc + 0][lr] = bv.x; Bs[lc + 1][lr] = bv.y;
        Bs[lc + 2][lr] = bv.z; Bs[lc + 3][lr] = bv.w;
        __syncthreads();
#pragma unroll
        for (int k = 0; k < 16; ++k) {
            float4 a = *(const float4*)&As[k][ty * 4];
            float4 b = *(const float4*)&Bs[k][tx * 4];
            acc[0][0] += a.x * b.x; acc[0][1] += a.x * b.y;
            acc[0][2] += a.x * b.z; acc[0][3] += a.x * b.w;
            acc[1][0] += a.y * b.x; acc[1][1] += a.y * b.y;
            acc[1][2] += a.y * b.z; acc[1][3] += a.y * b.w;
            acc[2][0] += a.z * b.x; acc[2][1] += a.z * b.y;
            acc[2][2] += a.z * b.z; acc[2][3] += a.z * b.w;
            acc[3][0] += a.w * b.x; acc[3][1] += a.w * b.y;
            acc[3][2] += a.w * b.z; acc[3][3] += a.w * b.w;
        }
    }

    int n = n0 + tx * 4;
    float bx_ = b1[n + 0] + b2[n + 0];
    float by_ = b1[n + 1] + b2[n + 1];
    float bz_ = b1[n + 2] + b2[n + 2];
    float bw_ = b1[n + 3] + b2[n + 3];
#pragma unroll
    for (int i = 0; i < 4; ++i) {
        int m = m0 + ty * 4 + i;
        float4 o;
        o.x = acc[i][0] + bx_; o.y = acc[i][1] + by_;
        o.z = acc[i][2] + bz_; o.w = acc[i][3] + bw_;
        *(float4*)(out + (size_t)m * HH + n) = o;
    }
}

// ---------------------------------------------------------------------------
// Fused 2-layer persistent recurrence, v10 = v9 (measured 1490us, VALU 52%)
// + two surgical idle-side changes:
//  (1) EARLY POLL: during phase X, after red-write and before the barrier,
//      spin-poll the NEXT phase's h data into registers (published ~1 phase
//      earlier -> slack ~1400cy > RT). Next phase starts with data in VGPRs:
//      stage -> FMA immediately, no load-wait at the phase head.
//      2-slot induction preserved: publish(bX,t+1) still requires this block
//      passed poll(bX,t), which requires all 8 rendezvous blocks published
//      tag t, which requires each passed poll(bX,t-1) -> overwritten slot
//      (tag t-1) already consumed by everyone.
//  (2) DISTRIBUTED FINALIZE: every wave finalizes 8 h0-rows + 8 h1-rows
//      (4 lanes/row: 2-4 red reads + 2 shfl_xor + leader tanh/publish,
//      ~100cy uniform) -> no straggler wave, no catch-up chain.
//
// Everything else byte-identical to v9: 256 blocks = 32 chunks(2 batches) x
// 8 slices(64 rows); 512 thr = 8 waves; lane r of wave w polls kown=w*64+r;
// wave-internal LDS staging + broadcast ds_read_b128 inner loop; redA/redB
// alternating reduce buffers (finalize of phase X completes before barrier
// of phase X+1; red_X rewritten only after that barrier -> race-free);
// 192 weight floats/thread; launch_bounds(512,2); tag-in-data exchange.
// ---------------------------------------------------------------------------
__device__ __forceinline__ void spin_poll(
    const ull* __restrict__ hp0, const ull* __restrict__ hp1,
    int slot, int bX, int kown, unsigned tt, ull& q0, ull& q1) {
    const ull* s0p = hp0 + (size_t)slot * BB * HH + (size_t)bX * HH + kown;
    const ull* s1p = hp1 + (size_t)slot * BB * HH + (size_t)bX * HH + kown;
    for (;;) {
        q0 = __hip_atomic_load(s0p, __ATOMIC_RELAXED, __HIP_MEMORY_SCOPE_AGENT);
        q1 = __hip_atomic_load(s1p, __ATOMIC_RELAXED, __HIP_MEMORY_SCOPE_AGENT);
        unsigned d = (((unsigned)(q0 >> 32)) ^ tt) | (((unsigned)(q1 >> 32)) ^ tt);
        if (d == 0) break;
    }
}

__device__ __forceinline__ void rec_phase10(
    int t, int bX, int tN, int bN, bool doNext,
    int r, int w, int kown, int wbase,
    int idx, int p, int grow0, int grow1, float bias1,
    const float* __restrict__ pre,
    const float4* wA, const float4* wI, const float4* wH,
    ull* __restrict__ hp0, ull* __restrict__ hp1,
    float* __restrict__ h0s, float* __restrict__ h1s,
    float (*red)[3][64],
    ull& qc0, ull& qc1,        // in: current phase data (tags == t)
    ull& qn0, ull& qn1,        // out: next phase data (tags == tN)
    float* __restrict__ y, float& h0last, float& h1last) {
    // pv prefetch for this phase's h0 finalize (leader lanes; hides latency)
    float pv = 0.f;
    if (p == 0 && idx < 8 && t < SS)
        pv = pre[((size_t)bX * SS + t) * HH + grow0];

    // stage current data (wave-internal segment; no barrier needed)
    h0s[kown] = __uint_as_float((unsigned)qc0);
    h1s[kown] = __uint_as_float((unsigned)qc1);
    asm volatile("" ::: "memory");

    // 3 matvec units over [wbase, wbase+64): broadcast b128 reads + fma
    const float4* x0 = (const float4*)&h0s[wbase];
    const float4* x1 = (const float4*)&h1s[wbase];
    float aa = 0.f, ai = 0.f, ah = 0.f;
#pragma unroll
    for (int i = 0; i < 16; ++i) {
        const float4 xv = x0[i];
        const float4 zv = x1[i];
        const float4 a4 = wA[i];
        const float4 i4 = wI[i];
        const float4 h4 = wH[i];
        aa = fmaf(a4.x, xv.x, aa); aa = fmaf(a4.y, xv.y, aa);
        aa = fmaf(a4.z, xv.z, aa); aa = fmaf(a4.w, xv.w, aa);
        ai = fmaf(i4.x, xv.x, ai); ai = fmaf(i4.y, xv.y, ai);
        ai = fmaf(i4.z, xv.z, ai); ai = fmaf(i4.w, xv.w, ai);
        ah = fmaf(h4.x, zv.x, ah); ah = fmaf(h4.y, zv.y, ah);
        ah = fmaf(h4.z, zv.z, ah); ah = fmaf(h4.w, zv.w, ah);
    }
    red[w][0][r] = aa; red[w][1][r] = ai; red[w][2][r] = ah;

    // early poll for the NEXT phase (its data published ~1 phase ago)
    if (doNext)
        spin_poll(hp0, hp1, tN & 1, bN, kown, (unsigned)tN, qn0, qn1);

    __syncthreads();

    // distributed finalize for (bX, t): wave w owns local rows [8w,8w+8)
    // for BOTH h0 (lanes idx<8) and h1 (lanes idx>=8); 4 lanes per row.
    if (idx < 8) {
        if (t < SS) {
            const int R = (w << 3) + idx;
            float s = red[2 * p][0][R] + red[2 * p + 1][0][R];
            s += __shfl_xor(s, 1);
            s += __shfl_xor(s, 2);
            if (p == 0) {
                float h0v = tanhf(pv + s);
                h0last = h0v;
                ull pk = ((ull)(unsigned)(t + 1) << 32) | (ull)__float_as_uint(h0v);
                __hip_atomic_store(&hp0[(size_t)((t + 1) & 1) * BB * HH + (size_t)bX * HH + grow0],
                                   pk, __ATOMIC_RELAXED, __HIP_MEMORY_SCOPE_AGENT);
            }
        }
    } else {
        const int R = (w << 3) + idx - 8;
        float si = red[2 * p][1][R] + red[2 * p + 1][1][R] +
                   red[2 * p][2][R] + red[2 * p + 1][2][R];
        si += __shfl_xor(si, 1);
        si += __shfl_xor(si, 2);
        if (p == 0) {
            float h1v = tanhf(si + bias1);
            h1last = h1v;
            y[((size_t)bX * SS + (t - 1)) * HH + grow1] = h1v;
            if (t < SS) {
                ull pk = ((ull)(unsigned)(t + 1) << 32) | (ull)__float_as_uint(h1v);
                __hip_atomic_store(&hp1[(size_t)((t + 1) & 1) * BB * HH + (size_t)bX * HH + grow1],
                                   pk, __ATOMIC_RELAXED, __HIP_MEMORY_SCOPE_AGENT);
            }
        }
    }
}

__global__ __launch_bounds__(512, 2) void k_rec10(
    const float* __restrict__ pre,       // [B][S][H] layer0 input projection
    const float* __restrict__ Whh0,
    const float* __restrict__ Wih1,
    const float* __restrict__ Whh1,
    const float* __restrict__ b_ih1,
    const float* __restrict__ b_hh1,
    float* __restrict__ y,               // [B][S][H] layer1 output
    float* __restrict__ hlast,           // [2][B][H]
    ull* __restrict__ hp0,
    ull* __restrict__ hp1) {
    __shared__ __align__(16) float h0s[HH], h1s[HH];
    __shared__ __align__(16) float redA[8][3][64], redB[8][3][64];

    const int tid = threadIdx.x;
    const int r = tid & 63;
    const int w = tid >> 6;              // k-eighth 0..7
    const int bid = blockIdx.x;
    const int g = bid & 7;               // row slice 0..7 (64 rows)
    const int c = bid >> 3;              // batch chunk 0..31
    const int grow = g * 64 + r;
    const int kown = w * 64 + r;         // polled k (both layers)
    const int wbase = w * 64;            // this wave's staged k segment
    const int bA = c * 2, bB = c * 2 + 1;

    // distributed-finalize lane roles: 4-lane groups, wave-local rows
    const int idx = r >> 2;              // 0..15
    const int p = r & 3;                 // part within group
    const int grow0 = g * 64 + (w << 3) + idx;        // h0 row (idx<8)
    const int grow1 = g * 64 + (w << 3) + (idx - 8);  // h1 row (idx>=8)

    // three 64x512 weight slices -> register file (192 floats, one-time)
    float4 wA[16], wI[16], wH[16];
    {
        const float* pA = Whh0 + (size_t)grow * HH + wbase;
        const float* pI = Wih1 + (size_t)grow * HH + wbase;
        const float* pH = Whh1 + (size_t)grow * HH + wbase;
#pragma unroll
        for (int i = 0; i < 16; ++i) {
            wA[i] = *(const float4*)(pA + i * 4);
            wI[i] = *(const float4*)(pI + i * 4);
            wH[i] = *(const float4*)(pH + i * 4);
        }
    }
    float bias1 = 0.f;
    if (idx >= 8) bias1 = b_ih1[grow1] + b_hh1[grow1];

    // ---- prologue: per batch, h0(0)=tanh(pre[0]) tag 1; h1(-1)=0 tag 1 ----
    float h0lA = 0.f, h0lB = 0.f, h1lA = 0.f, h1lB = 0.f;
    if (w == 0) {
        float pA0 = pre[(size_t)bA * SS * HH + grow];
        float v = tanhf(pA0);
        ull pk = (1ULL << 32) | (ull)__float_as_uint(v);
        __hip_atomic_store(&hp0[(size_t)1 * BB * HH + (size_t)bA * HH + grow], pk,
                           __ATOMIC_RELAXED, __HIP_MEMORY_SCOPE_AGENT);
        float pB0 = pre[(size_t)bB * SS * HH + grow];
        v = tanhf(pB0);
        pk = (1ULL << 32) | (ull)__float_as_uint(v);
        __hip_atomic_store(&hp0[(size_t)1 * BB * HH + (size_t)bB * HH + grow], pk,
                           __ATOMIC_RELAXED, __HIP_MEMORY_SCOPE_AGENT);
    } else if (w == 1) {
        ull pk = (1ULL << 32);           // h1(-1) = 0
        __hip_atomic_store(&hp1[(size_t)1 * BB * HH + (size_t)bA * HH + grow], pk,
                           __ATOMIC_RELAXED, __HIP_MEMORY_SCOPE_AGENT);
        __hip_atomic_store(&hp1[(size_t)1 * BB * HH + (size_t)bB * HH + grow], pk,
                           __ATOMIC_RELAXED, __HIP_MEMORY_SCOPE_AGENT);
    }
    // seed h0last from prologue (leaders track h0(0) until first finalize)
    if (p == 0 && idx < 8) {
        h0lA = tanhf(pre[(size_t)bA * SS * HH + grow0]);
        h0lB = tanhf(pre[(size_t)bB * SS * HH + grow0]);
    }

    // initial blocking poll for phase A of tick 1
    ull qa0, qa1, qb0, qb1;
    spin_poll(hp0, hp1, 1, bA, kown, 1u, qa0, qa1);

    for (int t = 1; t <= SS; ++t) {
        // phase A: compute (bA,t) with qa; early-poll (bB,t) -> qb
        rec_phase10(t, bA, t, bB, true, r, w, kown, wbase, idx, p,
                    grow0, grow1, bias1, pre, wA, wI, wH, hp0, hp1,
                    h0s, h1s, redA, qa0, qa1, qb0, qb1, y, h0lA, h1lA);
        // phase B: compute (bB,t) with qb; early-poll (bA,t+1) -> qa
        rec_phase10(t, bB, t + 1, bA, (t < SS), r, w, kown, wbase, idx, p,
                    grow0, grow1, bias1, pre, wA, wI, wH, hp0, hp1,
                    h0s, h1s, redB, qb0, qb1, qa0, qa1, y, h0lB, h1lB);
    }

    // epilogue: leaders hold the final states
    if (p == 0 && idx < 8) {
        hlast[(size_t)bA * HH + grow0] = h0lA;                       // layer0
        hlast[(size_t)bB * HH + grow0] = h0lB;
    } else if (p == 0 && idx >= 8) {
        hlast[(size_t)BB * HH + (size_t)bA * HH + grow1] = h1lA;     // layer1
        hlast[(size_t)BB * HH + (size_t)bB * HH + grow1] = h1lB;
    }
}

// ---------------------------------------------------------------------------
extern "C" void kernel_launch(void* const* d_in, const int* in_sizes, int n_in,
                              void* d_out, int out_size, void* d_ws, size_t ws_size,
                              hipStream_t stream) {
    const int*   src   = (const int*)d_in[0];
    const float* emb   = (const float*)d_in[1];
    const float* W_ih0 = (const float*)d_in[2];
    const float* W_hh0 = (const float*)d_in[3];
    const float* b_ih0 = (const float*)d_in[4];
    const float* b_hh0 = (const float*)d_in[5];
    const float* W_ih1 = (const float*)d_in[6];
    const float* W_hh1 = (const float*)d_in[7];
    const float* b_ih1 = (const float*)d_in[8];
    const float* b_hh1 = (const float*)d_in[9];

    float* out   = (float*)d_out;
    float* y_out = out;                               // [B][S][H] (layer1 y)
    float* hlast = out + (size_t)BB * SS * HH;        // [2][B][H]

    float* ws  = (float*)d_ws;
    float* pre = ws;                                  // [B][S][H] layer0 proj
    ull* hp0 = (ull*)(ws + (size_t)BB * SS * HH);
    ull* hp1 = hp0 + (size_t)2 * BB * HH;

    // Layer-0 input projection (embedding gather fused in)
    k_proj<EE><<<dim3(512, 8), 256, 0, stream>>>(nullptr, src, emb, W_ih0,
                                                 b_ih0, b_hh0, pre);
    // Fused 2-layer recurrence: v9 + early poll + distributed finalize
    k_rec10<<<256, 512, 0, stream>>>(pre, W_hh0, W_ih1, W_hh1, b_ih1, b_hh1,
                                     y_out, hlast, hp0, hp1);
}

// Round 18
// 2230.859 us; speedup vs baseline: 1.3178x; 1.3178x over previous
//
#include <hip/hip_runtime.h>
#include <math.h>

#define BB 64
#define SS 512
#define EE 256
#define HH 512

typedef unsigned long long ull;

// ---------------------------------------------------------------------------
// Projection GEMM (layer 0): out[m][n] = sum_k A[m][k]*Wih[n][k] + b1 + b2
// ---------------------------------------------------------------------------
template <int K>
__global__ __launch_bounds__(256) void k_proj(const float* __restrict__ Ain,
                                              const int* __restrict__ src,
                                              const float* __restrict__ emb,
                                              const float* __restrict__ Wih,
                                              const float* __restrict__ b1,
                                              const float* __restrict__ b2,
                                              float* __restrict__ out) {
    __shared__ __align__(16) float As[16][68];
    __shared__ __align__(16) float Bs[16][68];
    int tid = threadIdx.x;
    int m0 = blockIdx.x * 64;
    int n0 = blockIdx.y * 64;
    int tx = tid & 15, ty = tid >> 4;
    int lr = tid >> 2;
    int lc = (tid & 3) * 4;

    const float* arow;
    if (src) arow = emb + (size_t)src[m0 + lr] * EE;
    else     arow = Ain + (size_t)(m0 + lr) * K;
    const float* brow = Wih + (size_t)(n0 + lr) * K;

    float acc[4][4] = {};

    for (int k0 = 0; k0 < K; k0 += 16) {
        float4 av = *(const float4*)(arow + k0 + lc);
        float4 bv = *(const float4*)(brow + k0 + lc);
        __syncthreads();
        As[lc + 0][lr] = av.x; As[lc + 1][lr] = av.y;
        As[lc + 2][lr] = av.z; As[lc + 3][lr] = av.w;
        Bs[lc + 0][lr] = bv.x; Bs[lc + 1][lr] = bv.y;
        Bs[lc + 2][lr] = bv.z; Bs[lc + 3][lr] = bv.w;
        __syncthreads();
#pragma unroll
        for (int k = 0; k < 16; ++k) {
            float4 a = *(const float4*)&As[k][ty * 4];
            float4 b = *(const float4*)&Bs[k][tx * 4];
            acc[0][0] += a.x * b.x; acc[0][1] += a.x * b.y;
            acc[0][2] += a.x * b.z; acc[0][3] += a.x * b.w;
            acc[1][0] += a.y * b.x; acc[1][1] += a.y * b.y;
            acc[1][2] += a.y * b.z; acc[1][3] += a.y * b.w;
            acc[2][0] += a.z * b.x; acc[2][1] += a.z * b.y;
            acc[2][2] += a.z * b.z; acc[2][3] += a.z * b.w;
            acc[3][0] += a.w * b.x; acc[3][1] += a.w * b.y;
            acc[3][2] += a.w * b.z; acc[3][3] += a.w * b.w;
        }
    }

    int n = n0 + tx * 4;
    float bx_ = b1[n + 0] + b2[n + 0];
    float by_ = b1[n + 1] + b2[n + 1];
    float bz_ = b1[n + 2] + b2[n + 2];
    float bw_ = b1[n + 3] + b2[n + 3];
#pragma unroll
    for (int i = 0; i < 4; ++i) {
        int m = m0 + ty * 4 + i;
        float4 o;
        o.x = acc[i][0] + bx_; o.y = acc[i][1] + by_;
        o.z = acc[i][2] + bz_; o.w = acc[i][3] + bw_;
        *(float4*)(out + (size_t)m * HH + n) = o;
    }
}

// ---------------------------------------------------------------------------
// Fused 2-layer persistent recurrence, v11 = v9 (measured 1490us, VALU 52%,
// 0 bank conflicts) + SPLIT POLL: issue next-phase tag-loads early (after
// staging, before the FMA block -> they fly during the ~1400cy FMA window),
// VALIDATE them after finalize (past the barrier). Hit case: zero RT at the
// phase head. Miss case: fallback spin = v9's cost, blocking only this
// wave's next red-write (v9's dependency graph — NOT v10's barrier-coupled
// one, which collapsed to 2820us; v10's distributed finalize also added
// 3.8e7 LDS bank conflicts, so finalize reverts to v9's wave-0/1 form).
//
// v9 recap (all preserved): 256 blocks = 32 chunks(2 batches) x 8 slices
// (64 rows); 512 thr = 8 waves; lane r of wave w polls kown = w*64+r in
// both hp0/hp1; batch-phased A/B ticks; wave-internal LDS staging +
// broadcast ds_read_b128 inner loop; redA/redB reduce, one barrier/phase;
// finalize wave 0 -> h0(t), wave 1 -> h1(t-1); 192 weight floats/thread;
// launch_bounds(512,2); tag-in-data {f32,u32 tag} 8B relaxed agent atomics,
// 2-slot per-layer buffers, 2-slot induction per batch chain.
// ---------------------------------------------------------------------------
__device__ __forceinline__ void spin_poll(
    const ull* __restrict__ hp0, const ull* __restrict__ hp1,
    int slot, int bX, int kown, unsigned tt, ull& q0, ull& q1) {
    const ull* s0p = hp0 + (size_t)slot * BB * HH + (size_t)bX * HH + kown;
    const ull* s1p = hp1 + (size_t)slot * BB * HH + (size_t)bX * HH + kown;
    for (;;) {
        q0 = __hip_atomic_load(s0p, __ATOMIC_RELAXED, __HIP_MEMORY_SCOPE_AGENT);
        q1 = __hip_atomic_load(s1p, __ATOMIC_RELAXED, __HIP_MEMORY_SCOPE_AGENT);
        unsigned d = (((unsigned)(q0 >> 32)) ^ tt) | (((unsigned)(q1 >> 32)) ^ tt);
        if (d == 0) break;
    }
}

__device__ __forceinline__ void rec_phase11(
    int t, int bX, int tN, int bN, bool doNext,
    int grow, int r, int w, int kown, int wbase,
    const float* __restrict__ pre,
    const float4* wA, const float4* wI, const float4* wH, float bias1,
    ull* __restrict__ hp0, ull* __restrict__ hp1,
    float* __restrict__ h0s, float* __restrict__ h1s,
    float (*red)[3][64],
    ull& qc0, ull& qc1,        // in: current phase data (tags == t, validated)
    ull& qn0, ull& qn1,        // out: next phase data (validated here)
    float* __restrict__ y, float& h0last, float& h1last) {
    // pv prefetch for this phase's h0 finalize (wave 0; hides under FMA)
    float pv = 0.f;
    if (w == 0 && t < SS) pv = pre[((size_t)bX * SS + t) * HH + grow];

    // stage current data (wave-internal segment; no barrier needed)
    h0s[kown] = __uint_as_float((unsigned)qc0);
    h1s[kown] = __uint_as_float((unsigned)qc1);
    asm volatile("" ::: "memory");

    // EARLY ISSUE: next phase's tag-loads fly during the FMA window below.
    const ull* n0p = hp0;
    const ull* n1p = hp1;
    ull e0 = 0, e1 = 0;
    if (doNext) {
        n0p = hp0 + (size_t)(tN & 1) * BB * HH + (size_t)bN * HH + kown;
        n1p = hp1 + (size_t)(tN & 1) * BB * HH + (size_t)bN * HH + kown;
        e0 = __hip_atomic_load(n0p, __ATOMIC_RELAXED, __HIP_MEMORY_SCOPE_AGENT);
        e1 = __hip_atomic_load(n1p, __ATOMIC_RELAXED, __HIP_MEMORY_SCOPE_AGENT);
    }

    // 3 matvec units over [wbase, wbase+64): broadcast b128 reads + fma
    const float4* x0 = (const float4*)&h0s[wbase];
    const float4* x1 = (const float4*)&h1s[wbase];
    float aa = 0.f, ai = 0.f, ah = 0.f;
#pragma unroll
    for (int i = 0; i < 16; ++i) {
        const float4 xv = x0[i];
        const float4 zv = x1[i];
        const float4 a4 = wA[i];
        const float4 i4 = wI[i];
        const float4 h4 = wH[i];
        aa = fmaf(a4.x, xv.x, aa); aa = fmaf(a4.y, xv.y, aa);
        aa = fmaf(a4.z, xv.z, aa); aa = fmaf(a4.w, xv.w, aa);
        ai = fmaf(i4.x, xv.x, ai); ai = fmaf(i4.y, xv.y, ai);
        ai = fmaf(i4.z, xv.z, ai); ai = fmaf(i4.w, xv.w, ai);
        ah = fmaf(h4.x, zv.x, ah); ah = fmaf(h4.y, zv.y, ah);
        ah = fmaf(h4.z, zv.z, ah); ah = fmaf(h4.w, zv.w, ah);
    }
    red[w][0][r] = aa; red[w][1][r] = ai; red[w][2][r] = ah;
    __syncthreads();

    // finalize (v9 form): wave 0 -> h0_X(t); wave 1 -> h1_X(t-1)
    if (w == 0) {
        if (t < SS) {
            float s0 = red[0][0][r] + red[1][0][r] + red[2][0][r] + red[3][0][r] +
                       red[4][0][r] + red[5][0][r] + red[6][0][r] + red[7][0][r];
            float h0v = tanhf(pv + s0);
            h0last = h0v;
            ull pk = ((ull)(unsigned)(t + 1) << 32) | (ull)__float_as_uint(h0v);
            __hip_atomic_store(&hp0[(size_t)((t + 1) & 1) * BB * HH + (size_t)bX * HH + grow],
                               pk, __ATOMIC_RELAXED, __HIP_MEMORY_SCOPE_AGENT);
        }
    } else if (w == 1) {
        float si = red[0][1][r] + red[1][1][r] + red[2][1][r] + red[3][1][r] +
                   red[4][1][r] + red[5][1][r] + red[6][1][r] + red[7][1][r];
        float sh = red[0][2][r] + red[1][2][r] + red[2][2][r] + red[3][2][r] +
                   red[4][2][r] + red[5][2][r] + red[6][2][r] + red[7][2][r];
        float h1v = tanhf(si + sh + bias1);
        h1last = h1v;
        y[((size_t)bX * SS + (t - 1)) * HH + grow] = h1v;
        if (t < SS) {
            ull pk = ((ull)(unsigned)(t + 1) << 32) | (ull)__float_as_uint(h1v);
            __hip_atomic_store(&hp1[(size_t)((t + 1) & 1) * BB * HH + (size_t)bX * HH + grow],
                               pk, __ATOMIC_RELAXED, __HIP_MEMORY_SCOPE_AGENT);
        }
    }

    // VALIDATE next-phase data (past the barrier -> no chain coupling;
    // a miss blocks only this wave, exactly like v9's phase-head poll)
    if (doNext) {
        const unsigned ttN = (unsigned)tN;
        unsigned d = (((unsigned)(e0 >> 32)) ^ ttN) | (((unsigned)(e1 >> 32)) ^ ttN);
        while (d != 0) {
            e0 = __hip_atomic_load(n0p, __ATOMIC_RELAXED, __HIP_MEMORY_SCOPE_AGENT);
            e1 = __hip_atomic_load(n1p, __ATOMIC_RELAXED, __HIP_MEMORY_SCOPE_AGENT);
            d = (((unsigned)(e0 >> 32)) ^ ttN) | (((unsigned)(e1 >> 32)) ^ ttN);
        }
        qn0 = e0; qn1 = e1;
    }
}

__global__ __launch_bounds__(512, 2) void k_rec11(
    const float* __restrict__ pre,       // [B][S][H] layer0 input projection
    const float* __restrict__ Whh0,
    const float* __restrict__ Wih1,
    const float* __restrict__ Whh1,
    const float* __restrict__ b_ih1,
    const float* __restrict__ b_hh1,
    float* __restrict__ y,               // [B][S][H] layer1 output
    float* __restrict__ hlast,           // [2][B][H]
    ull* __restrict__ hp0,
    ull* __restrict__ hp1) {
    __shared__ __align__(16) float h0s[HH], h1s[HH];
    __shared__ __align__(16) float redA[8][3][64], redB[8][3][64];

    const int tid = threadIdx.x;
    const int r = tid & 63;
    const int w = tid >> 6;              // k-eighth 0..7
    const int bid = blockIdx.x;
    const int g = bid & 7;               // row slice 0..7 (64 rows)
    const int c = bid >> 3;              // batch chunk 0..31
    const int grow = g * 64 + r;
    const int kown = w * 64 + r;         // polled k (both layers)
    const int wbase = w * 64;            // this wave's staged k segment
    const int bA = c * 2, bB = c * 2 + 1;

    // three 64x512 weight slices -> register file (192 floats, one-time)
    float4 wA[16], wI[16], wH[16];
    {
        const float* pA = Whh0 + (size_t)grow * HH + wbase;
        const float* pI = Wih1 + (size_t)grow * HH + wbase;
        const float* pH = Whh1 + (size_t)grow * HH + wbase;
#pragma unroll
        for (int i = 0; i < 16; ++i) {
            wA[i] = *(const float4*)(pA + i * 4);
            wI[i] = *(const float4*)(pI + i * 4);
            wH[i] = *(const float4*)(pH + i * 4);
        }
    }

    // ---- prologue: per batch, h0(0)=tanh(pre[0]) tag 1; h1(-1)=0 tag 1 ----
    float h0lA = 0.f, h0lB = 0.f, h1lA = 0.f, h1lB = 0.f, bias1 = 0.f;
    if (w == 0) {
        float pA0 = pre[(size_t)bA * SS * HH + grow];
        h0lA = tanhf(pA0);
        ull pk = (1ULL << 32) | (ull)__float_as_uint(h0lA);
        __hip_atomic_store(&hp0[(size_t)1 * BB * HH + (size_t)bA * HH + grow], pk,
                           __ATOMIC_RELAXED, __HIP_MEMORY_SCOPE_AGENT);
        float pB0 = pre[(size_t)bB * SS * HH + grow];
        h0lB = tanhf(pB0);
        pk = (1ULL << 32) | (ull)__float_as_uint(h0lB);
        __hip_atomic_store(&hp0[(size_t)1 * BB * HH + (size_t)bB * HH + grow], pk,
                           __ATOMIC_RELAXED, __HIP_MEMORY_SCOPE_AGENT);
    } else if (w == 1) {
        bias1 = b_ih1[grow] + b_hh1[grow];
        ull pk = (1ULL << 32);           // h1(-1) = 0
        __hip_atomic_store(&hp1[(size_t)1 * BB * HH + (size_t)bA * HH + grow], pk,
                           __ATOMIC_RELAXED, __HIP_MEMORY_SCOPE_AGENT);
        __hip_atomic_store(&hp1[(size_t)1 * BB * HH + (size_t)bB * HH + grow], pk,
                           __ATOMIC_RELAXED, __HIP_MEMORY_SCOPE_AGENT);
    }

    // initial blocking poll for phase A of tick 1
    ull qa0, qa1, qb0 = 0, qb1 = 0;
    spin_poll(hp0, hp1, 1, bA, kown, 1u, qa0, qa1);

    for (int t = 1; t <= SS; ++t) {
        // phase A: compute (bA,t) with qa; early-issue+validate (bB,t) -> qb
        rec_phase11(t, bA, t, bB, true, grow, r, w, kown, wbase, pre,
                    wA, wI, wH, bias1, hp0, hp1, h0s, h1s, redA,
                    qa0, qa1, qb0, qb1, y, h0lA, h1lA);
        // phase B: compute (bB,t) with qb; early-issue+validate (bA,t+1) -> qa
        rec_phase11(t, bB, t + 1, bA, (t < SS), grow, r, w, kown, wbase, pre,
                    wA, wI, wH, bias1, hp0, hp1, h0s, h1s, redB,
                    qb0, qb1, qa0, qa1, y, h0lB, h1lB);
    }

    if (w == 0) {
        hlast[(size_t)bA * HH + grow] = h0lA;                        // layer0
        hlast[(size_t)bB * HH + grow] = h0lB;
    } else if (w == 1) {
        hlast[(size_t)BB * HH + (size_t)bA * HH + grow] = h1lA;      // layer1
        hlast[(size_t)BB * HH + (size_t)bB * HH + grow] = h1lB;
    }
}

// ---------------------------------------------------------------------------
extern "C" void kernel_launch(void* const* d_in, const int* in_sizes, int n_in,
                              void* d_out, int out_size, void* d_ws, size_t ws_size,
                              hipStream_t stream) {
    const int*   src   = (const int*)d_in[0];
    const float* emb   = (const float*)d_in[1];
    const float* W_ih0 = (const float*)d_in[2];
    const float* W_hh0 = (const float*)d_in[3];
    const float* b_ih0 = (const float*)d_in[4];
    const float* b_hh0 = (const float*)d_in[5];
    const float* W_ih1 = (const float*)d_in[6];
    const float* W_hh1 = (const float*)d_in[7];
    const float* b_ih1 = (const float*)d_in[8];
    const float* b_hh1 = (const float*)d_in[9];

    float* out   = (float*)d_out;
    float* y_out = out;                               // [B][S][H] (layer1 y)
    float* hlast = out + (size_t)BB * SS * HH;        // [2][B][H]

    float* ws  = (float*)d_ws;
    float* pre = ws;                                  // [B][S][H] layer0 proj
    ull* hp0 = (ull*)(ws + (size_t)BB * SS * HH);
    ull* hp1 = hp0 + (size_t)2 * BB * HH;

    // Layer-0 input projection (embedding gather fused in)
    k_proj<EE><<<dim3(512, 8), 256, 0, stream>>>(nullptr, src, emb, W_ih0,
                                                 b_ih0, b_hh0, pre);
    // Fused 2-layer recurrence: v9 + split poll (issue early, validate late)
    k_rec11<<<256, 512, 0, stream>>>(pre, W_hh0, W_ih1, W_hh1, b_ih1, b_hh1,
                                     y_out, hlast, hp0, hp1);
}

// Round 19
// 1566.136 us; speedup vs baseline: 1.8771x; 1.4244x over previous
//
#include <hip/hip_runtime.h>
#include <math.h>

#define BB 64
#define SS 512
#define EE 256
#define HH 512

typedef unsigned long long ull;

// ---------------------------------------------------------------------------
// Projection GEMM (layer 0): out[m][n] = sum_k A[m][k]*Wih[n][k] + b1 + b2
// ---------------------------------------------------------------------------
template <int K>
__global__ __launch_bounds__(256) void k_proj(const float* __restrict__ Ain,
                                              const int* __restrict__ src,
                                              const float* __restrict__ emb,
                                              const float* __restrict__ Wih,
                                              const float* __restrict__ b1,
                                              const float* __restrict__ b2,
                                              float* __restrict__ out) {
    __shared__ __align__(16) float As[16][68];
    __shared__ __align__(16) float Bs[16][68];
    int tid = threadIdx.x;
    int m0 = blockIdx.x * 64;
    int n0 = blockIdx.y * 64;
    int tx = tid & 15, ty = tid >> 4;
    int lr = tid >> 2;
    int lc = (tid & 3) * 4;

    const float* arow;
    if (src) arow = emb + (size_t)src[m0 + lr] * EE;
    else     arow = Ain + (size_t)(m0 + lr) * K;
    const float* brow = Wih + (size_t)(n0 + lr) * K;

    float acc[4][4] = {};

    for (int k0 = 0; k0 < K; k0 += 16) {
        float4 av = *(const float4*)(arow + k0 + lc);
        float4 bv = *(const float4*)(brow + k0 + lc);
        __syncthreads();
        As[lc + 0][lr] = av.x; As[lc + 1][lr] = av.y;
        As[lc + 2][lr] = av.z; As[lc + 3][lr] = av.w;
        Bs[lc + 0][lr] = bv.x; Bs[lc + 1][lr] = bv.y;
        Bs[lc + 2][lr] = bv.z; Bs[lc + 3][lr] = bv.w;
        __syncthreads();
#pragma unroll
        for (int k = 0; k < 16; ++k) {
            float4 a = *(const float4*)&As[k][ty * 4];
            float4 b = *(const float4*)&Bs[k][tx * 4];
            acc[0][0] += a.x * b.x; acc[0][1] += a.x * b.y;
            acc[0][2] += a.x * b.z; acc[0][3] += a.x * b.w;
            acc[1][0] += a.y * b.x; acc[1][1] += a.y * b.y;
            acc[1][2] += a.y * b.z; acc[1][3] += a.y * b.w;
            acc[2][0] += a.z * b.x; acc[2][1] += a.z * b.y;
            acc[2][2] += a.z * b.z; acc[2][3] += a.z * b.w;
            acc[3][0] += a.w * b.x; acc[3][1] += a.w * b.y;
            acc[3][2] += a.w * b.z; acc[3][3] += a.w * b.w;
        }
    }

    int n = n0 + tx * 4;
    float bx_ = b1[n + 0] + b2[n + 0];
    float by_ = b1[n + 1] + b2[n + 1];
    float bz_ = b1[n + 2] + b2[n + 2];
    float bw_ = b1[n + 3] + b2[n + 3];
#pragma unroll
    for (int i = 0; i < 4; ++i) {
        int m = m0 + ty * 4 + i;
        float4 o;
        o.x = acc[i][0] + bx_; o.y = acc[i][1] + by_;
        o.z = acc[i][2] + bz_; o.w = acc[i][3] + bw_;
        *(float4*)(out + (size_t)m * HH + n) = o;
    }
}

// ---------------------------------------------------------------------------
// Fused 2-layer persistent recurrence, v12 = v9 (measured 1490us — the
// validated local optimum) + XCD-ALIGNED RENDEZVOUS, the only change:
//
//   v9:  g = bid & 7,  c = bid >> 3  -> a chunk's 8 blocks land on 8
//        DIFFERENT XCDs (bid%8 round-robin) -> every publish->poll crosses
//        the die through IC at maximal coherence distance.
//   v12: g = bid >> 5, c = bid & 31  -> a chunk's 8 blocks all have
//        bid = c (mod 8) -> SAME XCD; 4 chunks x 8 blocks = 32 CUs/XCD,
//        perfectly balanced. Pure index remap; protocol, schedule, and
//        instruction stream byte-identical to v9 -> clean A/B on placement.
//
// v9 recap (all preserved): 256 blocks = 32 chunks(2 batches) x 8 slices
// (64 rows); 512 thr = 8 waves; lane r of wave w polls kown = w*64+r in
// both hp0/hp1; batch-phased A/B ticks; wave-internal LDS staging +
// broadcast ds_read_b128 inner loop; redA/redB reduce, one barrier/phase;
// finalize wave 0 -> h0(t), wave 1 -> h1(t-1); 192 weight floats/thread;
// launch_bounds(512,2); tag-in-data {f32,u32 tag} 8B relaxed agent atomics,
// 2-slot per-layer buffers, 2-slot induction per batch chain; poison 0xAA
// never matches tags 1..512. Correctness does NOT depend on the bid->XCD
// mapping (it's a locality heuristic only).
// ---------------------------------------------------------------------------
__device__ __forceinline__ void rec_phase12(
    int t, int bX, int grow, int r, int w, int kown, int wbase,
    const float* __restrict__ pre,
    const float4* wA, const float4* wI, const float4* wH, float bias1,
    ull* __restrict__ hp0, ull* __restrict__ hp1,
    float* __restrict__ h0s, float* __restrict__ h1s,
    float (*red)[3][64],
    float* __restrict__ y, float& h0last, float& h1last) {
    // prefetch this batch's pre value (finalize waves only; hides under poll)
    float pv = 0.f;
    if (w == 0 && t < SS) pv = pre[((size_t)bX * SS + t) * HH + grow];

    // poll own k in both layer buffers (tags must equal t)
    const ull* s0p = hp0 + (size_t)(t & 1) * BB * HH + (size_t)bX * HH + kown;
    const ull* s1p = hp1 + (size_t)(t & 1) * BB * HH + (size_t)bX * HH + kown;
    ull q0, q1;
    const unsigned tt = (unsigned)t;
    for (;;) {
        q0 = __hip_atomic_load(s0p, __ATOMIC_RELAXED, __HIP_MEMORY_SCOPE_AGENT);
        q1 = __hip_atomic_load(s1p, __ATOMIC_RELAXED, __HIP_MEMORY_SCOPE_AGENT);
        unsigned d = (((unsigned)(q0 >> 32)) ^ tt) | (((unsigned)(q1 >> 32)) ^ tt);
        if (d == 0) break;
    }
    // wave-internal staging: this wave's 64-k segment, consumed only by this
    // wave's own lanes -> no barrier (in-order DS pipe; compiler fence).
    h0s[kown] = __uint_as_float((unsigned)q0);
    h1s[kown] = __uint_as_float((unsigned)q1);
    asm volatile("" ::: "memory");

    // 3 matvec units over [wbase, wbase+64): broadcast b128 reads + fma
    const float4* x0 = (const float4*)&h0s[wbase];
    const float4* x1 = (const float4*)&h1s[wbase];
    float aa = 0.f, ai = 0.f, ah = 0.f;
#pragma unroll
    for (int i = 0; i < 16; ++i) {
        const float4 xv = x0[i];
        const float4 zv = x1[i];
        const float4 a4 = wA[i];
        const float4 i4 = wI[i];
        const float4 h4 = wH[i];
        aa = fmaf(a4.x, xv.x, aa); aa = fmaf(a4.y, xv.y, aa);
        aa = fmaf(a4.z, xv.z, aa); aa = fmaf(a4.w, xv.w, aa);
        ai = fmaf(i4.x, xv.x, ai); ai = fmaf(i4.y, xv.y, ai);
        ai = fmaf(i4.z, xv.z, ai); ai = fmaf(i4.w, xv.w, ai);
        ah = fmaf(h4.x, zv.x, ah); ah = fmaf(h4.y, zv.y, ah);
        ah = fmaf(h4.z, zv.z, ah); ah = fmaf(h4.w, zv.w, ah);
    }
    red[w][0][r] = aa; red[w][1][r] = ai; red[w][2][r] = ah;
    __syncthreads();

    // finalize: wave 0 -> h0_X(t); wave 1 -> h1_X(t-1); others run ahead
    if (w == 0) {
        if (t < SS) {
            float s0 = red[0][0][r] + red[1][0][r] + red[2][0][r] + red[3][0][r] +
                       red[4][0][r] + red[5][0][r] + red[6][0][r] + red[7][0][r];
            float h0v = tanhf(pv + s0);
            h0last = h0v;
            ull pk = ((ull)(unsigned)(t + 1) << 32) | (ull)__float_as_uint(h0v);
            __hip_atomic_store(&hp0[(size_t)((t + 1) & 1) * BB * HH + (size_t)bX * HH + grow],
                               pk, __ATOMIC_RELAXED, __HIP_MEMORY_SCOPE_AGENT);
        }
    } else if (w == 1) {
        float si = red[0][1][r] + red[1][1][r] + red[2][1][r] + red[3][1][r] +
                   red[4][1][r] + red[5][1][r] + red[6][1][r] + red[7][1][r];
        float sh = red[0][2][r] + red[1][2][r] + red[2][2][r] + red[3][2][r] +
                   red[4][2][r] + red[5][2][r] + red[6][2][r] + red[7][2][r];
        float h1v = tanhf(si + sh + bias1);
        h1last = h1v;
        y[((size_t)bX * SS + (t - 1)) * HH + grow] = h1v;
        if (t < SS) {
            ull pk = ((ull)(unsigned)(t + 1) << 32) | (ull)__float_as_uint(h1v);
            __hip_atomic_store(&hp1[(size_t)((t + 1) & 1) * BB * HH + (size_t)bX * HH + grow],
                               pk, __ATOMIC_RELAXED, __HIP_MEMORY_SCOPE_AGENT);
        }
    }
}

__global__ __launch_bounds__(512, 2) void k_rec12(
    const float* __restrict__ pre,       // [B][S][H] layer0 input projection
    const float* __restrict__ Whh0,
    const float* __restrict__ Wih1,
    const float* __restrict__ Whh1,
    const float* __restrict__ b_ih1,
    const float* __restrict__ b_hh1,
    float* __restrict__ y,               // [B][S][H] layer1 output
    float* __restrict__ hlast,           // [2][B][H]
    ull* __restrict__ hp0,
    ull* __restrict__ hp1) {
    __shared__ __align__(16) float h0s[HH], h1s[HH];
    __shared__ __align__(16) float redA[8][3][64], redB[8][3][64];

    const int tid = threadIdx.x;
    const int r = tid & 63;
    const int w = tid >> 6;              // k-eighth 0..7
    const int bid = blockIdx.x;
    const int g = bid >> 5;              // row slice 0..7 (XCD-aligned remap)
    const int c = bid & 31;              // batch chunk 0..31 (bid%8 = c%8 = XCD)
    const int grow = g * 64 + r;
    const int kown = w * 64 + r;         // polled k (both layers)
    const int wbase = w * 64;            // this wave's staged k segment
    const int bA = c * 2, bB = c * 2 + 1;

    // three 64x512 weight slices -> register file (192 floats, one-time)
    float4 wA[16], wI[16], wH[16];
    {
        const float* pA = Whh0 + (size_t)grow * HH + wbase;
        const float* pI = Wih1 + (size_t)grow * HH + wbase;
        const float* pH = Whh1 + (size_t)grow * HH + wbase;
#pragma unroll
        for (int i = 0; i < 16; ++i) {
            wA[i] = *(const float4*)(pA + i * 4);
            wI[i] = *(const float4*)(pI + i * 4);
            wH[i] = *(const float4*)(pH + i * 4);
        }
    }

    // ---- prologue: per batch, h0(0)=tanh(pre[0]) tag 1; h1(-1)=0 tag 1 ----
    float h0lA = 0.f, h0lB = 0.f, h1lA = 0.f, h1lB = 0.f, bias1 = 0.f;
    if (w == 0) {
        float pA0 = pre[(size_t)bA * SS * HH + grow];
        h0lA = tanhf(pA0);
        ull pk = (1ULL << 32) | (ull)__float_as_uint(h0lA);
        __hip_atomic_store(&hp0[(size_t)1 * BB * HH + (size_t)bA * HH + grow], pk,
                           __ATOMIC_RELAXED, __HIP_MEMORY_SCOPE_AGENT);
        float pB0 = pre[(size_t)bB * SS * HH + grow];
        h0lB = tanhf(pB0);
        pk = (1ULL << 32) | (ull)__float_as_uint(h0lB);
        __hip_atomic_store(&hp0[(size_t)1 * BB * HH + (size_t)bB * HH + grow], pk,
                           __ATOMIC_RELAXED, __HIP_MEMORY_SCOPE_AGENT);
    } else if (w == 1) {
        bias1 = b_ih1[grow] + b_hh1[grow];
        ull pk = (1ULL << 32);           // h1(-1) = 0
        __hip_atomic_store(&hp1[(size_t)1 * BB * HH + (size_t)bA * HH + grow], pk,
                           __ATOMIC_RELAXED, __HIP_MEMORY_SCOPE_AGENT);
        __hip_atomic_store(&hp1[(size_t)1 * BB * HH + (size_t)bB * HH + grow], pk,
                           __ATOMIC_RELAXED, __HIP_MEMORY_SCOPE_AGENT);
    }

    for (int t = 1; t <= SS; ++t) {
        // phase A (batch 2c): tag-t data published one B-phase ago
        rec_phase12(t, bA, grow, r, w, kown, wbase, pre, wA, wI, wH, bias1,
                    hp0, hp1, h0s, h1s, redA, y, h0lA, h1lA);
        // phase B (batch 2c+1): tag-t data published one A-phase ago
        rec_phase12(t, bB, grow, r, w, kown, wbase, pre, wA, wI, wH, bias1,
                    hp0, hp1, h0s, h1s, redB, y, h0lB, h1lB);
    }

    if (w == 0) {
        hlast[(size_t)bA * HH + grow] = h0lA;                        // layer0
        hlast[(size_t)bB * HH + grow] = h0lB;
    } else if (w == 1) {
        hlast[(size_t)BB * HH + (size_t)bA * HH + grow] = h1lA;      // layer1
        hlast[(size_t)BB * HH + (size_t)bB * HH + grow] = h1lB;
    }
}

// ---------------------------------------------------------------------------
extern "C" void kernel_launch(void* const* d_in, const int* in_sizes, int n_in,
                              void* d_out, int out_size, void* d_ws, size_t ws_size,
                              hipStream_t stream) {
    const int*   src   = (const int*)d_in[0];
    const float* emb   = (const float*)d_in[1];
    const float* W_ih0 = (const float*)d_in[2];
    const float* W_hh0 = (const float*)d_in[3];
    const float* b_ih0 = (const float*)d_in[4];
    const float* b_hh0 = (const float*)d_in[5];
    const float* W_ih1 = (const float*)d_in[6];
    const float* W_hh1 = (const float*)d_in[7];
    const float* b_ih1 = (const float*)d_in[8];
    const float* b_hh1 = (const float*)d_in[9];

    float* out   = (float*)d_out;
    float* y_out = out;                               // [B][S][H] (layer1 y)
    float* hlast = out + (size_t)BB * SS * HH;        // [2][B][H]

    float* ws  = (float*)d_ws;
    float* pre = ws;                                  // [B][S][H] layer0 proj
    ull* hp0 = (ull*)(ws + (size_t)BB * SS * HH);
    ull* hp1 = hp0 + (size_t)2 * BB * HH;

    // Layer-0 input projection (embedding gather fused in)
    k_proj<EE><<<dim3(512, 8), 256, 0, stream>>>(nullptr, src, emb, W_ih0,
                                                 b_ih0, b_hh0, pre);
    // Fused 2-layer recurrence: v9 + XCD-aligned rendezvous placement
    k_rec12<<<256, 512, 0, stream>>>(pre, W_hh0, W_ih1, W_hh1, b_ih1, b_hh1,
                                     y_out, hlast, hp0, hp1);
}